// Round 1
// baseline (194.567 us; speedup 1.0000x reference)
//
#include <hip/hip_runtime.h>
#include <utility>

#define NQ   7
#define DIM  128
#define HALF 64            // state elements per lane (2 lanes per row)
#define RPB  32            // rows per block (1 wave)

// static_for: constexpr indices in initial IR -> first SROA scalarizes arrays.
template<class F, int... I>
__device__ __forceinline__ void static_for_impl(F&& f, std::integer_sequence<int, I...>) {
    (f(std::integral_constant<int, I>{}), ...);
}
template<int N, class F>
__device__ __forceinline__ void static_for(F&& f) {
    static_for_impl(static_cast<F&&>(f), std::make_integer_sequence<int, N>{});
}

// swap with adjacent lane (2t <-> 2t+1): v_mov_b32 dpp quad_perm:[1,0,3,2]
__device__ __forceinline__ float swap_adj(float x) {
    int v = __builtin_amdgcn_update_dpp(0, __builtin_bit_cast(int, x),
                                        0xB1 /*quad_perm [1,0,3,2]*/,
                                        0xF, 0xF, true);
    return __builtin_bit_cast(float, v);
}

// 2 lanes per row: lane 2t+h owns elements [h*64, h*64+64) of row t.
// Staging: global_load_lds (no VGPR round-trip, no ds_write). LDS dest must be
// lane-linear (rule #21), so bank-conflict avoidance moves from pad-33 to an
// XOR involution pi(x) = x ^ ((x>>5)&7) on the f4 index, applied BOTH to the
// per-lane global source (stage) and to the read address. Each 1KB load still
// covers exactly f4 [64j, 64j+64) (lane permutation only -> fully coalesced);
// the read spreads t across all 8 16B bank-groups (8 lanes/group, uniform).
__global__ __launch_bounds__(64, 2)
void qnat_kernel(const float* __restrict__ embed,
                 const float* __restrict__ theta,
                 float* __restrict__ out)
{
    __shared__ float4 tile[RPB * 32];                  // 16384 B, LINEAR
    const int lane = threadIdx.x;                      // 0..63
    const int t = lane >> 1;                           // row within block
    const int h = lane & 1;                            // half of the row
    const float4* __restrict__ g4 =
        reinterpret_cast<const float4*>(embed) + (size_t)blockIdx.x * (RPB * 32);

    // ---- async stage-in: 16 x 1KB direct global->LDS ----
    const int b5 = lane >> 5;
    static_for<16>([&](auto J) {
        constexpr int j = J.value;
        const int m  = (2 * j + b5) & 7;               // ((64j+lane)>>5)&7
        const int sf = 64 * j + (lane ^ m);            // pi(64j+lane)
        __builtin_amdgcn_global_load_lds(
            (const __attribute__((address_space(1))) void*)(g4 + sf),
            (__attribute__((address_space(3))) void*)(&tile[64 * j]),
            16, 0, 0);
    });

    // ---- trig (wave-uniform) hoisted here: hides under the HBM latency ----
    float c_[2 * NQ], s_[2 * NQ];
    static_for<2 * NQ>([&](auto G) {
        constexpr int g = G.value;
        const float ha = 0.5f * theta[g];
        c_[g] = __cosf(ha);
        s_[g] = __sinf(ha);
    });

    asm volatile("s_waitcnt vmcnt(0)" ::: "memory");   // belt-and-braces drain
    __syncthreads();

    // ---- LDS -> registers, same involution on the read address ----
    float st[HALF];
    const int tl = t & 7;
    static_for<16>([&](auto J) {                       // ds_read_b128 x16
        constexpr int j = J.value;
        const float4 v = tile[t * 32 + h * 16 + (j ^ tl)];
        st[4 * j + 0] = v.x;
        st[4 * j + 1] = v.y;
        st[4 * j + 2] = v.z;
        st[4 * j + 3] = v.w;
    });
    // NOTE: no upfront norm pass. The circuit is unitary, so sum(probs) at the
    // end equals |row|^2 exactly up to fp error; the Walsh tree computes it.

    const float hs = h ? -1.f : 1.f;

    // ---- 2 layers of 7 RY gates; CZ only after layer 0 (layer-1 CZ is a
    //      diagonal +-1 immediately squared away -> dead code) ----
    static_for<2>([&](auto D) {
        constexpr int d = D.value;
        // q = 0..5: pairs stay within the lane's half
        static_for<6>([&](auto Q) {
            constexpr int q = Q.value;
            const float cc = c_[d * NQ + q], sn = s_[d * NQ + q];
            static_for<32>([&](auto P) {
                constexpr int p  = P.value;
                constexpr int lo = 1 << q;
                constexpr int i0 = ((p >> q) << (q + 1)) | (p & (lo - 1));
                constexpr int i1 = i0 | lo;
                const float a0 = st[i0], a1 = st[i1];
                st[i0] = fmaf(cc, a0, -sn * a1);
                st[i1] = fmaf(sn, a0,  cc * a1);
            });
        });
        // q = 6: partner lane holds the other half-row
        {
            const float cc = c_[d * NQ + 6], sn = s_[d * NQ + 6];
            const float sgn = h ? sn : -sn;   // h=0: c*a0 - s*a1 ; h=1: s*a0 + c*a1
            static_for<HALF>([&](auto J) {
                constexpr int j = J.value;
                const float other = swap_adj(st[j]);
                st[j] = fmaf(sgn, other, cc * st[j]);
            });
        }
        if constexpr (d == 0) {
            // CZ: global g = h*64+j; parity = popcount(j&(j>>1)) ^ (bit5(j)&h)
            static_for<HALF>([&](auto J) {
                constexpr int j = J.value;
                if constexpr ((__builtin_popcount(j & (j >> 1)) & 1) == 1) st[j] = -st[j];
                if constexpr (((j >> 5) & 1) == 1) st[j] *= hs;   // bit5*bit6 term
            });
        }
    });

    // ---- probs (unnormalized) ----
    static_for<HALF>([&](auto J) {
        constexpr int j = J.value;
        st[j] *= st[j];
    });

    // ---- Walsh: o[k] = 2*S_even - T (T = level-invariant total) ----
    float o[NQ];
    float Se = 0.f, So = 0.f;
    static_for<32>([&](auto I) {                       // level 0 + total
        constexpr int i = I.value;
        const float a = st[2 * i], b = st[2 * i + 1];
        Se += a; So += b;
        st[i] = a + b;                                 // write i <= read 2i: safe
    });
    o[0] = Se - So;
    const float T = Se + So;                           // local sum of probs
    static_for<5>([&](auto K) {
        constexpr int k = K.value + 1;
        constexpr int n = HALF >> (k + 1);
        float S = 0.f;
        static_for<16>([&](auto I) {
            constexpr int i = I.value;
            if constexpr (i < n) {
                const float a = st[2 * i], b = st[2 * i + 1];
                S += a;
                st[i] = a + b;
            }
        });
        o[k] = fmaf(2.f, S, -T);
    });
    static_for<6>([&](auto K) {
        constexpr int k = K.value;
        o[k] += swap_adj(o[k]);                        // sum both halves
    });
    const float Tsw = swap_adj(T);
    o[6] = hs * (T - Tsw);                             // = T(h=0) - T(h=1)
    const float invss = __builtin_amdgcn_rcpf(T + Tsw);  // = 1/|row|^2 (unitary)
    static_for<NQ>([&](auto K) { o[K.value] *= invss; });

    // ---- repack through LDS for coalesced stores (224 floats/block) ----
    __syncthreads();
    float* ldsf = reinterpret_cast<float*>(tile);
    if (h == 0) {
        static_for<NQ>([&](auto K) {
            constexpr int k = K.value;
            ldsf[t * NQ + k] = o[k];
        });
    }
    __syncthreads();
    float* __restrict__ ob = out + (size_t)blockIdx.x * (RPB * NQ);
    static_for<4>([&](auto It) {
        constexpr int it = It.value;
        const int idx = it * 64 + lane;
        if constexpr (it < 3) {
            ob[idx] = ldsf[idx];
        } else {
            if (idx < RPB * NQ) ob[idx] = ldsf[idx];
        }
    });
}

extern "C" void kernel_launch(void* const* d_in, const int* in_sizes, int n_in,
                              void* d_out, int out_size, void* d_ws, size_t ws_size,
                              hipStream_t stream)
{
    const float* embed = (const float*)d_in[0];
    const float* theta = (const float*)d_in[1];
    float* out = (float*)d_out;
    const int batch = in_sizes[0] / DIM;          // 262144
    dim3 grid(batch / RPB), block(64);
    hipLaunchKernelGGL(qnat_kernel, grid, block, 0, stream, embed, theta, out);
}